// Round 1
// baseline (764.174 us; speedup 1.0000x reference)
//
#include <hip/hip_runtime.h>
#include <hip/hip_bf16.h>

#define NN 8192
#define EE 65536

typedef unsigned short u16;

__device__ __forceinline__ unsigned short f2bf(float f) {
  __hip_bfloat16 h = __float2bfloat16(f);
  return *reinterpret_cast<unsigned short*>(&h);
}

// ---------------------------------------------------------------------------
// Generic fp32 tiled GEMM: OUT[row][col] = post( scale * sum_k X[row][k]*W[k][col] )
// X element (row,k) at X[row*xrs + xco + k*xes]; W row-major (K x NOUT).
// Tile: 128 rows x 64 cols, 256 threads, 8x4 accumulators per thread.
// ---------------------------------------------------------------------------
template<bool SILU, bool OUT_BF16>
__global__ __launch_bounds__(256) void k_gemm(
    const float* __restrict__ X, int xrs, int xes, int xco,
    const float* __restrict__ W, int K, int NOUT,
    float scale, void* __restrict__ OUTv, int ors,
    const float* __restrict__ dens)
{
  __shared__ float Xs[128 * 65];
  __shared__ float Ws[64 * 64];
  const int tid  = threadIdx.x;
  const int row0 = blockIdx.x * 128;
  const int col0 = blockIdx.y * 64;
  const int ci = tid & 15;       // col group: cols ci*4 .. ci*4+3
  const int ri = tid >> 4;       // row group: rows ri*8 .. ri*8+7
  float acc[8][4] = {};

  for (int k0 = 0; k0 < K; k0 += 64) {
    const int kc  = (K - k0 >= 64) ? 64 : (K - k0);   // 64 or 16 in this problem
    const int ksh = (kc == 64) ? 6 : 4;
    for (int idx = tid; idx < (kc << 7); idx += 256) {
      const int r = idx >> ksh, kk = idx & (kc - 1);
      Xs[r * 65 + kk] = X[(size_t)(row0 + r) * xrs + xco + (size_t)(k0 + kk) * xes];
    }
    for (int idx = tid; idx < (kc << 6); idx += 256) {
      const int kk = idx >> 6, c = idx & 63;
      Ws[kk * 64 + c] = W[(size_t)(k0 + kk) * NOUT + col0 + c];
    }
    __syncthreads();
    if (kc == 64) {
      #pragma unroll 8
      for (int kk = 0; kk < 64; ++kk) {
        const float4 wv = *reinterpret_cast<const float4*>(&Ws[kk * 64 + ci * 4]);
        #pragma unroll
        for (int j = 0; j < 8; ++j) {
          const float x = Xs[(ri * 8 + j) * 65 + kk];
          acc[j][0] += x * wv.x; acc[j][1] += x * wv.y;
          acc[j][2] += x * wv.z; acc[j][3] += x * wv.w;
        }
      }
    } else {
      for (int kk = 0; kk < kc; ++kk) {
        const float4 wv = *reinterpret_cast<const float4*>(&Ws[kk * 64 + ci * 4]);
        #pragma unroll
        for (int j = 0; j < 8; ++j) {
          const float x = Xs[(ri * 8 + j) * 65 + kk];
          acc[j][0] += x * wv.x; acc[j][1] += x * wv.y;
          acc[j][2] += x * wv.z; acc[j][3] += x * wv.w;
        }
      }
    }
    __syncthreads();
  }

  #pragma unroll
  for (int j = 0; j < 8; ++j) {
    const int row = row0 + ri * 8 + j;
    float post = 1.0f;
    if (dens) post = 1.0f / (dens[row] + 1.0f);
    float v[4];
    #pragma unroll
    for (int q = 0; q < 4; ++q) {
      float t = acc[j][q] * scale;
      if (SILU) t = t / (1.0f + __expf(-t));   // x * sigmoid(x)
      v[q] = t * post;
    }
    if (OUT_BF16) {
      ushort4 pk;
      pk.x = f2bf(v[0]); pk.y = f2bf(v[1]); pk.z = f2bf(v[2]); pk.w = f2bf(v[3]);
      *reinterpret_cast<ushort4*>(reinterpret_cast<u16*>(OUTv) +
          (size_t)row * ors + col0 + ci * 4) = pk;
    } else {
      *reinterpret_cast<float4*>(reinterpret_cast<float*>(OUTv) +
          (size_t)row * ors + col0 + ci * 4) = make_float4(v[0], v[1], v[2], v[3]);
    }
  }
}

// ---------------------------------------------------------------------------
// efm[e] = concat(edge_feats[e] (8), magmom_node_inv_feats[sender[e]] (8))
// ---------------------------------------------------------------------------
__global__ __launch_bounds__(256) void k_build_efm(
    const float* __restrict__ edge_feats, const float* __restrict__ mm_inv,
    const int* __restrict__ snd, float* __restrict__ efm)
{
  const int t = blockIdx.x * 256 + threadIdx.x;   // EE*4 threads
  const int e = t >> 2, q = t & 3;
  float4 val;
  if (q < 2) {
    val = reinterpret_cast<const float4*>(edge_feats)[e * 2 + q];
  } else {
    const int s = snd[e];
    val = reinterpret_cast<const float4*>(mm_inv)[s * 2 + (q - 2)];
  }
  reinterpret_cast<float4*>(efm)[e * 4 + q] = val;
}

// ---------------------------------------------------------------------------
// CSR build
// ---------------------------------------------------------------------------
__global__ __launch_bounds__(256) void k_count(const int* __restrict__ rcv, int* __restrict__ counts) {
  const int e = blockIdx.x * 256 + threadIdx.x;
  atomicAdd(&counts[rcv[e]], 1);
}

__global__ __launch_bounds__(1024) void k_scan(const int* __restrict__ counts,
                                               int* __restrict__ offs, int* __restrict__ cursor) {
  __shared__ int part[1024];
  const int tid = threadIdx.x;
  int local[8];
  int s = 0;
  #pragma unroll
  for (int j = 0; j < 8; ++j) { local[j] = s; s += counts[tid * 8 + j]; }
  part[tid] = s;
  __syncthreads();
  for (int off = 1; off < 1024; off <<= 1) {
    int v = 0;
    if (tid >= off) v = part[tid - off];
    __syncthreads();
    part[tid] += v;
    __syncthreads();
  }
  const int base = part[tid] - s;   // exclusive prefix at this thread's chunk
  #pragma unroll
  for (int j = 0; j < 8; ++j) {
    const int o = base + local[j];
    offs[tid * 8 + j] = o;
    cursor[tid * 8 + j] = o;
  }
  if (tid == 1023) offs[NN] = part[1023];
}

__global__ __launch_bounds__(256) void k_fill(const int* __restrict__ rcv,
                                              int* __restrict__ cursor, int* __restrict__ perm) {
  const int e = blockIdx.x * 256 + threadIdx.x;
  const int pos = atomicAdd(&cursor[rcv[e]], 1);
  perm[pos] = e;
}

// ---------------------------------------------------------------------------
// Gather: one wave per node, lane = channel u. Accumulates the 5 scalar and
// 8 vector tensor-product slots in registers; writes ms/mv/density once.
// ---------------------------------------------------------------------------
__global__ __launch_bounds__(256) void k_gather(
    const int* __restrict__ snd_idx,
    const float* __restrict__ edge_attrs,
    const float* __restrict__ edge_feats,
    const float* __restrict__ mm_attrs,
    const float* __restrict__ dens_w,
    const float* __restrict__ s_buf,
    const float* __restrict__ v_buf,
    const __hip_bfloat16* __restrict__ tp,
    const __hip_bfloat16* __restrict__ wmb,
    const int* __restrict__ offs,
    const int* __restrict__ perm,
    float* __restrict__ ms,
    float* __restrict__ mv,
    float* __restrict__ dens)
{
  const int n = (blockIdx.x * 256 + threadIdx.x) >> 6;
  const int lane = threadIdx.x & 63;
  if (n >= NN) return;
  float dw[8];
  #pragma unroll
  for (int r = 0; r < 8; ++r) dw[r] = dens_w[r];
  float acc_s[5] = {0.f, 0.f, 0.f, 0.f, 0.f};
  float acc_v[8][3] = {};
  float dacc = 0.f;
  const int start = offs[n], end = offs[n + 1];
  for (int idx = start; idx < end; ++idx) {
    const int e = perm[idx];
    const int s = snd_idx[e];
    const float y0  = edge_attrs[e * 4 + 0];
    const float y1x = edge_attrs[e * 4 + 1];
    const float y1y = edge_attrs[e * 4 + 2];
    const float y1z = edge_attrs[e * 4 + 3];
    const float m0  = mm_attrs[s * 4 + 0];
    const float m1x = mm_attrs[s * 4 + 1];
    const float m1y = mm_attrs[s * 4 + 2];
    const float m1z = mm_attrs[s * 4 + 3];
    float q = 0.f;
    #pragma unroll
    for (int r = 0; r < 8; ++r) q += edge_feats[e * 8 + r] * dw[r];
    q *= 0.35355339059f;           // 1/sqrt(8)
    dacc += tanhf(q * q);
    const float xs  = s_buf[s * 64 + lane];
    const float xvx = v_buf[(s * 3 + 0) * 64 + lane];
    const float xvy = v_buf[(s * 3 + 1) * 64 + lane];
    const float xvz = v_buf[(s * 3 + 2) * 64 + lane];
    float tpv[5];
    #pragma unroll
    for (int j = 0; j < 5; ++j) tpv[j] = __bfloat162float(tp[(size_t)e * 320 + j * 64 + lane]);
    float wv[13];
    #pragma unroll
    for (int p = 0; p < 13; ++p) wv[p] = __bfloat162float(wmb[(size_t)e * 832 + p * 64 + lane]);

    const float ms0  = tpv[0] * xs * y0;
    const float mv0x = tpv[1] * xs * y1x, mv0y = tpv[1] * xs * y1y, mv0z = tpv[1] * xs * y1z;
    const float mv1x = tpv[2] * xvx * y0, mv1y = tpv[2] * xvy * y0, mv1z = tpv[2] * xvz * y0;
    const float ms1  = tpv[3] * (xvx * y1x + xvy * y1y + xvz * y1z) * 0.57735026919f;
    const float crx = xvy * y1z - xvz * y1y;
    const float cry = xvz * y1x - xvx * y1z;
    const float crz = xvx * y1y - xvy * y1x;
    const float mv2x = tpv[4] * crx * 0.70710678119f;
    const float mv2y = tpv[4] * cry * 0.70710678119f;
    const float mv2z = tpv[4] * crz * 0.70710678119f;

    acc_s[0]    += wv[0] * ms0 * m0;
    acc_v[0][0] += wv[1] * ms0 * m1x; acc_v[0][1] += wv[1] * ms0 * m1y; acc_v[0][2] += wv[1] * ms0 * m1z;
    acc_s[1]    += wv[2] * ms1 * m0;
    acc_v[1][0] += wv[3] * ms1 * m1x; acc_v[1][1] += wv[3] * ms1 * m1y; acc_v[1][2] += wv[3] * ms1 * m1z;

#define VV_BLOCK(vx, vy, vz, pw, vslotA, sslot, vslotB)                                   \
    acc_v[vslotA][0] += wv[pw] * (vx) * m0;                                               \
    acc_v[vslotA][1] += wv[pw] * (vy) * m0;                                               \
    acc_v[vslotA][2] += wv[pw] * (vz) * m0;                                               \
    acc_s[sslot] += wv[pw + 1] * ((vx) * m1x + (vy) * m1y + (vz) * m1z) * 0.57735026919f; \
    {                                                                                     \
      const float ccx = (vy) * m1z - (vz) * m1y;                                          \
      const float ccy = (vz) * m1x - (vx) * m1z;                                          \
      const float ccz = (vx) * m1y - (vy) * m1x;                                          \
      acc_v[vslotB][0] += wv[pw + 2] * ccx * 0.70710678119f;                              \
      acc_v[vslotB][1] += wv[pw + 2] * ccy * 0.70710678119f;                              \
      acc_v[vslotB][2] += wv[pw + 2] * ccz * 0.70710678119f;                              \
    }

    VV_BLOCK(mv0x, mv0y, mv0z, 4, 2, 2, 3)
    VV_BLOCK(mv1x, mv1y, mv1z, 7, 4, 3, 5)
    VV_BLOCK(mv2x, mv2y, mv2z, 10, 6, 4, 7)
#undef VV_BLOCK
  }
  #pragma unroll
  for (int j = 0; j < 5; ++j) ms[(size_t)n * 320 + j * 64 + lane] = acc_s[j];
  #pragma unroll
  for (int p = 0; p < 8; ++p)
    #pragma unroll
    for (int i = 0; i < 3; ++i)
      mv[((size_t)n * 3 + i) * 512 + p * 64 + lane] = acc_v[p][i];
  if (lane == 0) dens[n] = dacc;
}

// ---------------------------------------------------------------------------
// Skip contraction: o[n][w] = (1/fan) * sum_u sum_v c[n][u]*na[n][v]*S[u][v][w]
// One wave handles 4 nodes (weight loads amortized 4x). lane = w.
// Writes final output (N, 64, 4): [:, :, 0] = o_s, [:, :, 1..3] = o_v.
// ---------------------------------------------------------------------------
__global__ __launch_bounds__(256) void k_skip(
    const float* __restrict__ ms2, const float* __restrict__ mv2,
    const float* __restrict__ na,
    const float* __restrict__ Ss, const float* __restrict__ Sv,
    float* __restrict__ out)
{
  const int wave = (blockIdx.x * 256 + threadIdx.x) >> 6;
  const int lane = threadIdx.x & 63;
  const int nb = wave * 4;
  float nav[4][10];
  #pragma unroll
  for (int t = 0; t < 4; ++t)
    #pragma unroll
    for (int v = 0; v < 10; ++v) nav[t][v] = na[(nb + t) * 10 + v];
  float os[4] = {0.f, 0.f, 0.f, 0.f};
  float ov[4][3] = {};
  for (int u = 0; u < 64; ++u) {
    float ssr[10], svr[10];
    #pragma unroll
    for (int v = 0; v < 10; ++v) ssr[v] = Ss[(u * 10 + v) * 64 + lane];
    #pragma unroll
    for (int v = 0; v < 10; ++v) svr[v] = Sv[(u * 10 + v) * 64 + lane];
    #pragma unroll
    for (int t = 0; t < 4; ++t) {
      float bs = 0.f, bv = 0.f;
      #pragma unroll
      for (int v = 0; v < 10; ++v) { bs += nav[t][v] * ssr[v]; bv += nav[t][v] * svr[v]; }
      os[t] += ms2[(nb + t) * 64 + u] * bs;
      #pragma unroll
      for (int i = 0; i < 3; ++i) ov[t][i] += mv2[((nb + t) * 3 + i) * 64 + u] * bv;
    }
  }
  const float inv_fan = 0.03952847075f;   // 1/sqrt(64*10)
  #pragma unroll
  for (int t = 0; t < 4; ++t) {
    const int n = nb + t;
    const size_t base = ((size_t)(n * 64 + lane)) * 4;
    out[base + 0] = os[t] * inv_fan;
    out[base + 1] = ov[t][0] * inv_fan;
    out[base + 2] = ov[t][1] * inv_fan;
    out[base + 3] = ov[t][2] * inv_fan;
  }
}

// ---------------------------------------------------------------------------
extern "C" void kernel_launch(void* const* d_in, const int* in_sizes, int n_in,
                              void* d_out, int out_size, void* d_ws, size_t ws_size,
                              hipStream_t stream)
{
  const float* node_attrs = (const float*)d_in[0];
  const float* node_feats = (const float*)d_in[1];
  const float* edge_attrs = (const float*)d_in[2];
  const float* edge_feats = (const float*)d_in[3];
  const int*   edge_index = (const int*)d_in[4];
  const float* mm_inv     = (const float*)d_in[5];
  const float* mm_attrs   = (const float*)d_in[6];
  const float* W_up_s     = (const float*)d_in[7];
  const float* W_up_v     = (const float*)d_in[8];
  const float* w0         = (const float*)d_in[9];
  const float* w1         = (const float*)d_in[10];
  const float* w2         = (const float*)d_in[11];
  const float* w3         = (const float*)d_in[12];
  const float* mag_w      = (const float*)d_in[13];
  const float* dens_w     = (const float*)d_in[14];
  const float* lin_s      = (const float*)d_in[15];
  const float* lin_v      = (const float*)d_in[16];
  const float* skip_s     = (const float*)d_in[17];
  const float* skip_v     = (const float*)d_in[18];
  float* out = (float*)d_out;

  char* wp = (char*)d_ws;
  auto alloc = [&](size_t b) { char* p = wp; wp += (b + 255) & ~(size_t)255; return p; };
  float* s_buf  = (float*)alloc((size_t)NN * 64 * 4);    // [n][w]
  float* v_buf  = (float*)alloc((size_t)NN * 192 * 4);   // [n][i][w]
  float* efm    = (float*)alloc((size_t)EE * 16 * 4);
  float* h_a    = (float*)alloc((size_t)EE * 64 * 4);
  float* h_b    = (float*)alloc((size_t)EE * 64 * 4);
  u16*   tp     = (u16*)alloc((size_t)EE * 320 * 2);     // bf16
  u16*   wmb    = (u16*)alloc((size_t)EE * 832 * 2);     // bf16
  float* ms     = (float*)alloc((size_t)NN * 320 * 4);   // [n][j*64+u]
  float* mv     = (float*)alloc((size_t)NN * 1536 * 4);  // [n][i][p*64+u]
  float* ms2    = (float*)alloc((size_t)NN * 64 * 4);
  float* mv2    = (float*)alloc((size_t)NN * 192 * 4);   // [n][i][w]
  float* dens   = (float*)alloc((size_t)NN * 4);
  int*   counts = (int*)alloc((size_t)NN * 4);
  int*   offs   = (int*)alloc((size_t)(NN + 1) * 4);
  int*   cursor = (int*)alloc((size_t)NN * 4);
  int*   perm   = (int*)alloc((size_t)EE * 4);

  const int* snd = edge_index;
  const int* rcv = edge_index + EE;

  hipMemsetAsync(counts, 0, (size_t)NN * 4, stream);
  k_build_efm<<<EE * 4 / 256, 256, 0, stream>>>(edge_feats, mm_inv, snd, efm);
  k_count<<<EE / 256, 256, 0, stream>>>(rcv, counts);
  k_scan<<<1, 1024, 0, stream>>>(counts, offs, cursor);
  k_fill<<<EE / 256, 256, 0, stream>>>(rcv, cursor, perm);

  // node up-projections: s = nf[:, :64] @ W_up_s / 8 ; v per component
  k_gemm<false, false><<<dim3(NN / 128, 1), 256, 0, stream>>>(
      node_feats, 256, 1, 0, W_up_s, 64, 64, 0.125f, s_buf, 64, nullptr);
  for (int i = 0; i < 3; ++i)
    k_gemm<false, false><<<dim3(NN / 128, 1), 256, 0, stream>>>(
        node_feats, 256, 3, 64 + i, W_up_v, 64, 64, 0.125f, v_buf + i * 64, 192, nullptr);

  // edge radial MLP
  k_gemm<true,  false><<<dim3(EE / 128, 1),  256, 0, stream>>>(efm, 16, 1, 0, w0, 16, 64,  0.25f,  h_a, 64,  nullptr);
  k_gemm<true,  false><<<dim3(EE / 128, 1),  256, 0, stream>>>(h_a, 64, 1, 0, w1, 64, 64,  0.125f, h_b, 64,  nullptr);
  k_gemm<true,  false><<<dim3(EE / 128, 1),  256, 0, stream>>>(h_b, 64, 1, 0, w2, 64, 64,  0.125f, h_a, 64,  nullptr);
  k_gemm<false, true ><<<dim3(EE / 128, 5),  256, 0, stream>>>(h_a, 64, 1, 0, w3, 64, 320, 0.125f, tp,  320, nullptr);
  k_gemm<false, true ><<<dim3(EE / 128, 13), 256, 0, stream>>>(efm, 16, 1, 0, mag_w, 16, 832, 0.25f, wmb, 832, nullptr);

  // per-node gather + tensor product + segment sum (no atomics)
  k_gather<<<NN / 4, 256, 0, stream>>>(snd, edge_attrs, edge_feats, mm_attrs, dens_w,
                                       s_buf, v_buf,
                                       (const __hip_bfloat16*)tp, (const __hip_bfloat16*)wmb,
                                       offs, perm, ms, mv, dens);

  // node linears with density division fused in epilogue
  k_gemm<false, false><<<dim3(NN / 128, 1), 256, 0, stream>>>(
      ms, 320, 1, 0, lin_s, 320, 64, 0.05590169944f, ms2, 64, dens);
  for (int i = 0; i < 3; ++i)
    k_gemm<false, false><<<dim3(NN / 128, 1), 256, 0, stream>>>(
        mv + i * 512, 1536, 1, 0, lin_v, 512, 64, 0.04419417382f, mv2 + i * 64, 192, dens);

  // skip contraction -> final output (N, 64, 4)
  k_skip<<<NN / 16, 256, 0, stream>>>(ms2, mv2, node_attrs, skip_s, skip_v, out);
}

// Round 2
// 456.806 us; speedup vs baseline: 1.6729x; 1.6729x over previous
//
#include <hip/hip_runtime.h>
#include <hip/hip_bf16.h>

#define NN 8192
#define EE 65536

typedef unsigned short u16;

__device__ __forceinline__ unsigned short f2bf(float f) {
  __hip_bfloat16 h = __float2bfloat16(f);
  return *reinterpret_cast<unsigned short*>(&h);
}

// ---------------------------------------------------------------------------
// Generic fp32 tiled GEMM: OUT[row][col] = post( scale * sum_k X[row][k]*W[k][col] )
// X element (row,k) at X[row*xrs + xco + z*xcob + k*xes]; W row-major (K x NOUT).
// Tile: RT rows x 64 cols, 256 threads. blockIdx.z = batch (adds xcob to X col
// offset and oob to OUT column base). RT=128 for edge GEMMs (big grids),
// RT=32 for node GEMMs (grid >= 256 blocks on 256 CUs).
// ---------------------------------------------------------------------------
template<int RT, bool SILU, bool OUT_BF16>
__global__ __launch_bounds__(256) void k_gemm(
    const float* __restrict__ X, int xrs, int xes, int xco, int xcob,
    const float* __restrict__ W, int K, int NOUT,
    float scale, void* __restrict__ OUTv, int ors, int oob,
    const float* __restrict__ dens)
{
  constexpr int RPT = RT / 16;            // rows per thread
  __shared__ float Xs[RT * 65];
  __shared__ float Ws[64 * 64];
  const int tid  = threadIdx.x;
  const int row0 = blockIdx.x * RT;
  const int col0 = blockIdx.y * 64;
  const int z    = blockIdx.z;
  const int xc   = xco + z * xcob;
  const int oo   = z * oob;
  const int ci = tid & 15;                // cols ci*4 .. ci*4+3
  const int ri = tid >> 4;                // rows ri*RPT .. ri*RPT+RPT-1
  float acc[RPT][4] = {};

  for (int k0 = 0; k0 < K; k0 += 64) {
    const int kc  = (K - k0 >= 64) ? 64 : (K - k0);   // 64 or 16 here
    const int ksh = (kc == 64) ? 6 : 4;
    for (int idx = tid; idx < kc * RT; idx += 256) {
      const int r = idx >> ksh, kk = idx & (kc - 1);
      Xs[r * 65 + kk] = X[(size_t)(row0 + r) * xrs + xc + (size_t)(k0 + kk) * xes];
    }
    for (int idx = tid; idx < (kc << 6); idx += 256) {
      const int kk = idx >> 6, c = idx & 63;
      Ws[kk * 64 + c] = W[(size_t)(k0 + kk) * NOUT + col0 + c];
    }
    __syncthreads();
    if (kc == 64) {
      #pragma unroll 8
      for (int kk = 0; kk < 64; ++kk) {
        const float4 wv = *reinterpret_cast<const float4*>(&Ws[kk * 64 + ci * 4]);
        #pragma unroll
        for (int j = 0; j < RPT; ++j) {
          const float x = Xs[(ri * RPT + j) * 65 + kk];
          acc[j][0] += x * wv.x; acc[j][1] += x * wv.y;
          acc[j][2] += x * wv.z; acc[j][3] += x * wv.w;
        }
      }
    } else {
      for (int kk = 0; kk < kc; ++kk) {
        const float4 wv = *reinterpret_cast<const float4*>(&Ws[kk * 64 + ci * 4]);
        #pragma unroll
        for (int j = 0; j < RPT; ++j) {
          const float x = Xs[(ri * RPT + j) * 65 + kk];
          acc[j][0] += x * wv.x; acc[j][1] += x * wv.y;
          acc[j][2] += x * wv.z; acc[j][3] += x * wv.w;
        }
      }
    }
    __syncthreads();
  }

  #pragma unroll
  for (int j = 0; j < RPT; ++j) {
    const int row = row0 + ri * RPT + j;
    float post = 1.0f;
    if (dens) post = 1.0f / (dens[row] + 1.0f);
    float v[4];
    #pragma unroll
    for (int q = 0; q < 4; ++q) {
      float t = acc[j][q] * scale;
      if (SILU) t = t / (1.0f + __expf(-t));   // x * sigmoid(x)
      v[q] = t * post;
    }
    if (OUT_BF16) {
      ushort4 pk;
      pk.x = f2bf(v[0]); pk.y = f2bf(v[1]); pk.z = f2bf(v[2]); pk.w = f2bf(v[3]);
      *reinterpret_cast<ushort4*>(reinterpret_cast<u16*>(OUTv) +
          (size_t)row * ors + oo + col0 + ci * 4) = pk;
    } else {
      *reinterpret_cast<float4*>(reinterpret_cast<float*>(OUTv) +
          (size_t)row * ors + oo + col0 + ci * 4) = make_float4(v[0], v[1], v[2], v[3]);
    }
  }
}

// ---------------------------------------------------------------------------
// efm[e] = concat(edge_feats[e] (8), magmom_node_inv_feats[sender[e]] (8))
// ---------------------------------------------------------------------------
__global__ __launch_bounds__(256) void k_build_efm(
    const float* __restrict__ edge_feats, const float* __restrict__ mm_inv,
    const int* __restrict__ snd, float* __restrict__ efm)
{
  const int t = blockIdx.x * 256 + threadIdx.x;   // EE*4 threads
  const int e = t >> 2, q = t & 3;
  float4 val;
  if (q < 2) {
    val = reinterpret_cast<const float4*>(edge_feats)[e * 2 + q];
  } else {
    const int s = snd[e];
    val = reinterpret_cast<const float4*>(mm_inv)[s * 2 + (q - 2)];
  }
  reinterpret_cast<float4*>(efm)[e * 4 + q] = val;
}

// ---------------------------------------------------------------------------
// CSR build
// ---------------------------------------------------------------------------
__global__ __launch_bounds__(256) void k_count(const int* __restrict__ rcv, int* __restrict__ counts) {
  const int e = blockIdx.x * 256 + threadIdx.x;
  atomicAdd(&counts[rcv[e]], 1);
}

__global__ __launch_bounds__(1024) void k_scan(const int* __restrict__ counts,
                                               int* __restrict__ offs, int* __restrict__ cursor) {
  __shared__ int part[1024];
  const int tid = threadIdx.x;
  int local[8];
  int s = 0;
  #pragma unroll
  for (int j = 0; j < 8; ++j) { local[j] = s; s += counts[tid * 8 + j]; }
  part[tid] = s;
  __syncthreads();
  for (int off = 1; off < 1024; off <<= 1) {
    int v = 0;
    if (tid >= off) v = part[tid - off];
    __syncthreads();
    part[tid] += v;
    __syncthreads();
  }
  const int base = part[tid] - s;   // exclusive prefix at this thread's chunk
  #pragma unroll
  for (int j = 0; j < 8; ++j) {
    const int o = base + local[j];
    offs[tid * 8 + j] = o;
    cursor[tid * 8 + j] = o;
  }
  if (tid == 1023) offs[NN] = part[1023];
}

__global__ __launch_bounds__(256) void k_fill(const int* __restrict__ rcv,
                                              int* __restrict__ cursor, int* __restrict__ perm) {
  const int e = blockIdx.x * 256 + threadIdx.x;
  const int pos = atomicAdd(&cursor[rcv[e]], 1);
  perm[pos] = e;
}

// ---------------------------------------------------------------------------
// Gather: one wave per node, lane = channel u. Accumulates the 5 scalar and
// 8 vector tensor-product slots in registers; writes ms/mv/density once.
// ---------------------------------------------------------------------------
__global__ __launch_bounds__(256) void k_gather(
    const int* __restrict__ snd_idx,
    const float* __restrict__ edge_attrs,
    const float* __restrict__ edge_feats,
    const float* __restrict__ mm_attrs,
    const float* __restrict__ dens_w,
    const float* __restrict__ s_buf,
    const float* __restrict__ v_buf,
    const __hip_bfloat16* __restrict__ tp,
    const __hip_bfloat16* __restrict__ wmb,
    const int* __restrict__ offs,
    const int* __restrict__ perm,
    float* __restrict__ ms,
    float* __restrict__ mv,
    float* __restrict__ dens)
{
  const int n = (blockIdx.x * 256 + threadIdx.x) >> 6;
  const int lane = threadIdx.x & 63;
  if (n >= NN) return;
  float dw[8];
  #pragma unroll
  for (int r = 0; r < 8; ++r) dw[r] = dens_w[r];
  float acc_s[5] = {0.f, 0.f, 0.f, 0.f, 0.f};
  float acc_v[8][3] = {};
  float dacc = 0.f;
  const int start = offs[n], end = offs[n + 1];
  for (int idx = start; idx < end; ++idx) {
    const int e = perm[idx];
    const int s = snd_idx[e];
    const float y0  = edge_attrs[e * 4 + 0];
    const float y1x = edge_attrs[e * 4 + 1];
    const float y1y = edge_attrs[e * 4 + 2];
    const float y1z = edge_attrs[e * 4 + 3];
    const float m0  = mm_attrs[s * 4 + 0];
    const float m1x = mm_attrs[s * 4 + 1];
    const float m1y = mm_attrs[s * 4 + 2];
    const float m1z = mm_attrs[s * 4 + 3];
    float q = 0.f;
    #pragma unroll
    for (int r = 0; r < 8; ++r) q += edge_feats[e * 8 + r] * dw[r];
    q *= 0.35355339059f;           // 1/sqrt(8)
    dacc += tanhf(q * q);
    const float xs  = s_buf[s * 64 + lane];
    const float xvx = v_buf[(s * 3 + 0) * 64 + lane];
    const float xvy = v_buf[(s * 3 + 1) * 64 + lane];
    const float xvz = v_buf[(s * 3 + 2) * 64 + lane];
    float tpv[5];
    #pragma unroll
    for (int j = 0; j < 5; ++j) tpv[j] = __bfloat162float(tp[(size_t)e * 320 + j * 64 + lane]);
    float wv[13];
    #pragma unroll
    for (int p = 0; p < 13; ++p) wv[p] = __bfloat162float(wmb[(size_t)e * 832 + p * 64 + lane]);

    const float ms0  = tpv[0] * xs * y0;
    const float mv0x = tpv[1] * xs * y1x, mv0y = tpv[1] * xs * y1y, mv0z = tpv[1] * xs * y1z;
    const float mv1x = tpv[2] * xvx * y0, mv1y = tpv[2] * xvy * y0, mv1z = tpv[2] * xvz * y0;
    const float ms1  = tpv[3] * (xvx * y1x + xvy * y1y + xvz * y1z) * 0.57735026919f;
    const float crx = xvy * y1z - xvz * y1y;
    const float cry = xvz * y1x - xvx * y1z;
    const float crz = xvx * y1y - xvy * y1x;
    const float mv2x = tpv[4] * crx * 0.70710678119f;
    const float mv2y = tpv[4] * cry * 0.70710678119f;
    const float mv2z = tpv[4] * crz * 0.70710678119f;

    acc_s[0]    += wv[0] * ms0 * m0;
    acc_v[0][0] += wv[1] * ms0 * m1x; acc_v[0][1] += wv[1] * ms0 * m1y; acc_v[0][2] += wv[1] * ms0 * m1z;
    acc_s[1]    += wv[2] * ms1 * m0;
    acc_v[1][0] += wv[3] * ms1 * m1x; acc_v[1][1] += wv[3] * ms1 * m1y; acc_v[1][2] += wv[3] * ms1 * m1z;

#define VV_BLOCK(vx, vy, vz, pw, vslotA, sslot, vslotB)                                   \
    acc_v[vslotA][0] += wv[pw] * (vx) * m0;                                               \
    acc_v[vslotA][1] += wv[pw] * (vy) * m0;                                               \
    acc_v[vslotA][2] += wv[pw] * (vz) * m0;                                               \
    acc_s[sslot] += wv[pw + 1] * ((vx) * m1x + (vy) * m1y + (vz) * m1z) * 0.57735026919f; \
    {                                                                                     \
      const float ccx = (vy) * m1z - (vz) * m1y;                                          \
      const float ccy = (vz) * m1x - (vx) * m1z;                                          \
      const float ccz = (vx) * m1y - (vy) * m1x;                                          \
      acc_v[vslotB][0] += wv[pw + 2] * ccx * 0.70710678119f;                              \
      acc_v[vslotB][1] += wv[pw + 2] * ccy * 0.70710678119f;                              \
      acc_v[vslotB][2] += wv[pw + 2] * ccz * 0.70710678119f;                              \
    }

    VV_BLOCK(mv0x, mv0y, mv0z, 4, 2, 2, 3)
    VV_BLOCK(mv1x, mv1y, mv1z, 7, 4, 3, 5)
    VV_BLOCK(mv2x, mv2y, mv2z, 10, 6, 4, 7)
#undef VV_BLOCK
  }
  #pragma unroll
  for (int j = 0; j < 5; ++j) ms[(size_t)n * 320 + j * 64 + lane] = acc_s[j];
  #pragma unroll
  for (int p = 0; p < 8; ++p)
    #pragma unroll
    for (int i = 0; i < 3; ++i)
      mv[((size_t)n * 3 + i) * 512 + p * 64 + lane] = acc_v[p][i];
  if (lane == 0) dens[n] = dacc;
}

// ---------------------------------------------------------------------------
// Skip contraction: o[n][w] = (1/fan) * sum_u sum_v c[n][u]*na[n][v]*S[u][v][w]
// One wave handles 4 nodes (weight loads amortized 4x). lane = w.
// Writes final output (N, 64, 4): [:, :, 0] = o_s, [:, :, 1..3] = o_v.
// ---------------------------------------------------------------------------
__global__ __launch_bounds__(256) void k_skip(
    const float* __restrict__ ms2, const float* __restrict__ mv2,
    const float* __restrict__ na,
    const float* __restrict__ Ss, const float* __restrict__ Sv,
    float* __restrict__ out)
{
  const int wave = (blockIdx.x * 256 + threadIdx.x) >> 6;
  const int lane = threadIdx.x & 63;
  const int nb = wave * 4;
  float nav[4][10];
  #pragma unroll
  for (int t = 0; t < 4; ++t)
    #pragma unroll
    for (int v = 0; v < 10; ++v) nav[t][v] = na[(nb + t) * 10 + v];
  float os[4] = {0.f, 0.f, 0.f, 0.f};
  float ov[4][3] = {};
  for (int u = 0; u < 64; ++u) {
    float ssr[10], svr[10];
    #pragma unroll
    for (int v = 0; v < 10; ++v) ssr[v] = Ss[(u * 10 + v) * 64 + lane];
    #pragma unroll
    for (int v = 0; v < 10; ++v) svr[v] = Sv[(u * 10 + v) * 64 + lane];
    #pragma unroll
    for (int t = 0; t < 4; ++t) {
      float bs = 0.f, bv = 0.f;
      #pragma unroll
      for (int v = 0; v < 10; ++v) { bs += nav[t][v] * ssr[v]; bv += nav[t][v] * svr[v]; }
      os[t] += ms2[(nb + t) * 64 + u] * bs;
      #pragma unroll
      for (int i = 0; i < 3; ++i) ov[t][i] += mv2[((nb + t) * 3 + i) * 64 + u] * bv;
    }
  }
  const float inv_fan = 0.03952847075f;   // 1/sqrt(64*10)
  #pragma unroll
  for (int t = 0; t < 4; ++t) {
    const int n = nb + t;
    const size_t base = ((size_t)(n * 64 + lane)) * 4;
    out[base + 0] = os[t] * inv_fan;
    out[base + 1] = ov[t][0] * inv_fan;
    out[base + 2] = ov[t][1] * inv_fan;
    out[base + 3] = ov[t][2] * inv_fan;
  }
}

// ---------------------------------------------------------------------------
extern "C" void kernel_launch(void* const* d_in, const int* in_sizes, int n_in,
                              void* d_out, int out_size, void* d_ws, size_t ws_size,
                              hipStream_t stream)
{
  const float* node_attrs = (const float*)d_in[0];
  const float* node_feats = (const float*)d_in[1];
  const float* edge_attrs = (const float*)d_in[2];
  const float* edge_feats = (const float*)d_in[3];
  const int*   edge_index = (const int*)d_in[4];
  const float* mm_inv     = (const float*)d_in[5];
  const float* mm_attrs   = (const float*)d_in[6];
  const float* W_up_s     = (const float*)d_in[7];
  const float* W_up_v     = (const float*)d_in[8];
  const float* w0         = (const float*)d_in[9];
  const float* w1         = (const float*)d_in[10];
  const float* w2         = (const float*)d_in[11];
  const float* w3         = (const float*)d_in[12];
  const float* mag_w      = (const float*)d_in[13];
  const float* dens_w     = (const float*)d_in[14];
  const float* lin_s      = (const float*)d_in[15];
  const float* lin_v      = (const float*)d_in[16];
  const float* skip_s     = (const float*)d_in[17];
  const float* skip_v     = (const float*)d_in[18];
  float* out = (float*)d_out;

  char* wp = (char*)d_ws;
  auto alloc = [&](size_t b) { char* p = wp; wp += (b + 255) & ~(size_t)255; return p; };
  float* s_buf  = (float*)alloc((size_t)NN * 64 * 4);    // [n][w]
  float* v_buf  = (float*)alloc((size_t)NN * 192 * 4);   // [n][i][w]
  float* efm    = (float*)alloc((size_t)EE * 16 * 4);
  float* h_a    = (float*)alloc((size_t)EE * 64 * 4);
  float* h_b    = (float*)alloc((size_t)EE * 64 * 4);
  u16*   tp     = (u16*)alloc((size_t)EE * 320 * 2);     // bf16
  u16*   wmb    = (u16*)alloc((size_t)EE * 832 * 2);     // bf16
  float* ms     = (float*)alloc((size_t)NN * 320 * 4);   // [n][j*64+u]
  float* mv     = (float*)alloc((size_t)NN * 1536 * 4);  // [n][i][p*64+u]
  float* ms2    = (float*)alloc((size_t)NN * 64 * 4);
  float* mv2    = (float*)alloc((size_t)NN * 192 * 4);   // [n][i][w]
  float* dens   = (float*)alloc((size_t)NN * 4);
  int*   counts = (int*)alloc((size_t)NN * 4);
  int*   offs   = (int*)alloc((size_t)(NN + 1) * 4);
  int*   cursor = (int*)alloc((size_t)NN * 4);
  int*   perm   = (int*)alloc((size_t)EE * 4);

  const int* snd = edge_index;
  const int* rcv = edge_index + EE;

  hipMemsetAsync(counts, 0, (size_t)NN * 4, stream);
  k_build_efm<<<EE * 4 / 256, 256, 0, stream>>>(edge_feats, mm_inv, snd, efm);
  k_count<<<EE / 256, 256, 0, stream>>>(rcv, counts);
  k_scan<<<1, 1024, 0, stream>>>(counts, offs, cursor);
  k_fill<<<EE / 256, 256, 0, stream>>>(rcv, cursor, perm);

  // node up-projections: s = nf[:, :64] @ W_up_s / 8 ; v batched over i (z)
  k_gemm<32, false, false><<<dim3(NN / 32, 1, 1), 256, 0, stream>>>(
      node_feats, 256, 1, 0, 0, W_up_s, 64, 64, 0.125f, s_buf, 64, 0, nullptr);
  k_gemm<32, false, false><<<dim3(NN / 32, 1, 3), 256, 0, stream>>>(
      node_feats, 256, 3, 64, 1, W_up_v, 64, 64, 0.125f, v_buf, 192, 64, nullptr);

  // edge radial MLP
  k_gemm<128, true,  false><<<dim3(EE / 128, 1, 1),  256, 0, stream>>>(efm, 16, 1, 0, 0, w0, 16, 64,  0.25f,  h_a, 64,  0, nullptr);
  k_gemm<128, true,  false><<<dim3(EE / 128, 1, 1),  256, 0, stream>>>(h_a, 64, 1, 0, 0, w1, 64, 64,  0.125f, h_b, 64,  0, nullptr);
  k_gemm<128, true,  false><<<dim3(EE / 128, 1, 1),  256, 0, stream>>>(h_b, 64, 1, 0, 0, w2, 64, 64,  0.125f, h_a, 64,  0, nullptr);
  k_gemm<128, false, true ><<<dim3(EE / 128, 5, 1),  256, 0, stream>>>(h_a, 64, 1, 0, 0, w3, 64, 320, 0.125f, tp,  320, 0, nullptr);
  k_gemm<128, false, true ><<<dim3(EE / 128, 13, 1), 256, 0, stream>>>(efm, 16, 1, 0, 0, mag_w, 16, 832, 0.25f, wmb, 832, 0, nullptr);

  // per-node gather + tensor product + segment sum (no atomics)
  k_gather<<<NN / 4, 256, 0, stream>>>(snd, edge_attrs, edge_feats, mm_attrs, dens_w,
                                       s_buf, v_buf,
                                       (const __hip_bfloat16*)tp, (const __hip_bfloat16*)wmb,
                                       offs, perm, ms, mv, dens);

  // node linears with density division fused in epilogue; lin_v batched over i
  k_gemm<32, false, false><<<dim3(NN / 32, 1, 1), 256, 0, stream>>>(
      ms, 320, 1, 0, 0, lin_s, 320, 64, 0.05590169944f, ms2, 64, 0, dens);
  k_gemm<32, false, false><<<dim3(NN / 32, 1, 3), 256, 0, stream>>>(
      mv, 1536, 1, 0, 512, lin_v, 512, 64, 0.04419417382f, mv2, 192, 64, dens);

  // skip contraction -> final output (N, 64, 4)
  k_skip<<<NN / 16, 256, 0, stream>>>(ms2, mv2, node_attrs, skip_s, skip_v, out);
}

// Round 3
// 450.469 us; speedup vs baseline: 1.6964x; 1.0141x over previous
//
#include <hip/hip_runtime.h>
#include <hip/hip_bf16.h>

#define NN 8192
#define EE 65536

typedef unsigned short u16;
typedef __attribute__((ext_vector_type(8))) short bf16x8;   // 8 bf16 = 4 VGPRs
typedef __attribute__((ext_vector_type(4))) float f32x4;

__device__ __forceinline__ unsigned short f2bf(float f) {
  __hip_bfloat16 h = __float2bfloat16(f);
  return *reinterpret_cast<unsigned short*>(&h);
}

__device__ __forceinline__ void split2(float x, u16& h, u16& l) {
  __hip_bfloat16 bh = __float2bfloat16(x);
  h = *reinterpret_cast<u16*>(&bh);
  float r = x - __bfloat162float(bh);
  __hip_bfloat16 bl = __float2bfloat16(r);
  l = *reinterpret_cast<u16*>(&bl);
}

// ---------------------------------------------------------------------------
// MFMA GEMM with fp32-equivalent precision via 3-term bf16 split:
//   A*B ~= Ah*Bh + Ah*Bl + Al*Bh   (lo*lo term ~2^-18 relative, dropped)
// X row-major (stride xrs), W row-major K x NOUT. Tile 128x64, 4 waves.
// Wave w computes rows [w*32, w*32+32) x 64 cols as 2x4 grid of 16x16 MFMAs.
// K=16 inputs are zero-padded to one 32-wide K-step.
// ---------------------------------------------------------------------------
template<bool SILU, bool OUT_BF16>
__global__ __launch_bounds__(256) void k_mgemm(
    const float* __restrict__ X, int xrs,
    const float* __restrict__ W, int K, int NOUT,
    float scale, void* __restrict__ OUTv, int ors,
    const float* __restrict__ dens)
{
  __shared__ u16 Ah[128 * 40];   // rows padded 32->40 elems (80 B = 5x16 B)
  __shared__ u16 Al[128 * 40];
  __shared__ u16 Bh[64 * 40];    // stored transposed: Bt[n][k]
  __shared__ u16 Bl[64 * 40];
  const int tid  = threadIdx.x;
  const int row0 = blockIdx.x * 128;
  const int col0 = blockIdx.y * 64;
  const int wave = tid >> 6, lane = tid & 63;
  const int quad = lane >> 4, lrow = lane & 15;
  const int kbase = quad * 8;

  f32x4 acc[2][4] = {};

  for (int k0 = 0; k0 < K; k0 += 32) {
    // ---- stage A (128 x 32 fp32 -> split bf16), coalesced float4 reads ----
    #pragma unroll
    for (int i = 0; i < 4; ++i) {
      const int idx = tid + i * 256;          // 1024 float4 slots
      const int r = idx >> 3, c = idx & 7;
      float4 v = make_float4(0.f, 0.f, 0.f, 0.f);
      if (k0 + c * 4 < K)
        v = *reinterpret_cast<const float4*>(&X[(size_t)(row0 + r) * xrs + k0 + c * 4]);
      ushort4 hh, ll;
      split2(v.x, hh.x, ll.x); split2(v.y, hh.y, ll.y);
      split2(v.z, hh.z, ll.z); split2(v.w, hh.w, ll.w);
      *reinterpret_cast<ushort4*>(&Ah[r * 40 + c * 4]) = hh;
      *reinterpret_cast<ushort4*>(&Al[r * 40 + c * 4]) = ll;
    }
    // ---- stage B (32 x 64 fp32 -> split bf16, transposed) ----
    #pragma unroll
    for (int i = 0; i < 8; ++i) {
      const int idx = tid + i * 256;          // 2048 elems
      const int k = idx >> 6, n = idx & 63;
      float v = 0.f;
      if (k0 + k < K) v = W[(size_t)(k0 + k) * NOUT + col0 + n];
      u16 hh, ll;
      split2(v, hh, ll);
      Bh[n * 40 + k] = hh;
      Bl[n * 40 + k] = ll;
    }
    __syncthreads();

    bf16x8 fah[2], fal[2], fbh[4], fbl[4];
    #pragma unroll
    for (int mt = 0; mt < 2; ++mt) {
      const int ro = (wave * 32 + mt * 16 + lrow) * 40 + kbase;
      fah[mt] = *reinterpret_cast<const bf16x8*>(&Ah[ro]);
      fal[mt] = *reinterpret_cast<const bf16x8*>(&Al[ro]);
    }
    #pragma unroll
    for (int nt = 0; nt < 4; ++nt) {
      const int ro = (nt * 16 + lrow) * 40 + kbase;
      fbh[nt] = *reinterpret_cast<const bf16x8*>(&Bh[ro]);
      fbl[nt] = *reinterpret_cast<const bf16x8*>(&Bl[ro]);
    }
    #pragma unroll
    for (int mt = 0; mt < 2; ++mt)
      #pragma unroll
      for (int nt = 0; nt < 4; ++nt) {
        acc[mt][nt] = __builtin_amdgcn_mfma_f32_16x16x32_bf16(fah[mt], fbh[nt], acc[mt][nt], 0, 0, 0);
        acc[mt][nt] = __builtin_amdgcn_mfma_f32_16x16x32_bf16(fah[mt], fbl[nt], acc[mt][nt], 0, 0, 0);
        acc[mt][nt] = __builtin_amdgcn_mfma_f32_16x16x32_bf16(fal[mt], fbh[nt], acc[mt][nt], 0, 0, 0);
      }
    __syncthreads();
  }

  // ---- epilogue: C/D layout col=lane&15, row=quad*4+reg ----
  #pragma unroll
  for (int mt = 0; mt < 2; ++mt)
    #pragma unroll
    for (int nt = 0; nt < 4; ++nt)
      #pragma unroll
      for (int r = 0; r < 4; ++r) {
        const int grow = row0 + wave * 32 + mt * 16 + quad * 4 + r;
        const int gcol = col0 + nt * 16 + lrow;
        float t = acc[mt][nt][r] * scale;
        if (SILU) t = t / (1.0f + __expf(-t));
        if (dens) t *= 1.0f / (dens[grow] + 1.0f);
        if (OUT_BF16)
          reinterpret_cast<u16*>(OUTv)[(size_t)grow * ors + gcol] = f2bf(t);
        else
          reinterpret_cast<float*>(OUTv)[(size_t)grow * ors + gcol] = t;
      }
}

// ---------------------------------------------------------------------------
// fp32 tiled GEMM (kept for node-side GEMMs): OUT = post(scale * X@W)
// ---------------------------------------------------------------------------
template<int RT, bool SILU, bool OUT_BF16>
__global__ __launch_bounds__(256) void k_gemm(
    const float* __restrict__ X, int xrs, int xes, int xco, int xcob,
    const float* __restrict__ W, int K, int NOUT,
    float scale, void* __restrict__ OUTv, int ors, int oob,
    const float* __restrict__ dens)
{
  constexpr int RPT = RT / 16;
  __shared__ float Xs[RT * 65];
  __shared__ float Ws[64 * 64];
  const int tid  = threadIdx.x;
  const int row0 = blockIdx.x * RT;
  const int col0 = blockIdx.y * 64;
  const int z    = blockIdx.z;
  const int xc   = xco + z * xcob;
  const int oo   = z * oob;
  const int ci = tid & 15;
  const int ri = tid >> 4;
  float acc[RPT][4] = {};

  for (int k0 = 0; k0 < K; k0 += 64) {
    const int kc  = (K - k0 >= 64) ? 64 : (K - k0);
    const int ksh = (kc == 64) ? 6 : 4;
    for (int idx = tid; idx < kc * RT; idx += 256) {
      const int r = idx >> ksh, kk = idx & (kc - 1);
      Xs[r * 65 + kk] = X[(size_t)(row0 + r) * xrs + xc + (size_t)(k0 + kk) * xes];
    }
    for (int idx = tid; idx < (kc << 6); idx += 256) {
      const int kk = idx >> 6, c = idx & 63;
      Ws[kk * 64 + c] = W[(size_t)(k0 + kk) * NOUT + col0 + c];
    }
    __syncthreads();
    for (int kk = 0; kk < kc; ++kk) {
      const float4 wv = *reinterpret_cast<const float4*>(&Ws[kk * 64 + ci * 4]);
      #pragma unroll
      for (int j = 0; j < RPT; ++j) {
        const float x = Xs[(ri * RPT + j) * 65 + kk];
        acc[j][0] += x * wv.x; acc[j][1] += x * wv.y;
        acc[j][2] += x * wv.z; acc[j][3] += x * wv.w;
      }
    }
    __syncthreads();
  }

  #pragma unroll
  for (int j = 0; j < RPT; ++j) {
    const int row = row0 + ri * RPT + j;
    float post = 1.0f;
    if (dens) post = 1.0f / (dens[row] + 1.0f);
    float v[4];
    #pragma unroll
    for (int q = 0; q < 4; ++q) {
      float t = acc[j][q] * scale;
      if (SILU) t = t / (1.0f + __expf(-t));
      v[q] = t * post;
    }
    if (OUT_BF16) {
      ushort4 pk;
      pk.x = f2bf(v[0]); pk.y = f2bf(v[1]); pk.z = f2bf(v[2]); pk.w = f2bf(v[3]);
      *reinterpret_cast<ushort4*>(reinterpret_cast<u16*>(OUTv) +
          (size_t)row * ors + oo + col0 + ci * 4) = pk;
    } else {
      *reinterpret_cast<float4*>(reinterpret_cast<float*>(OUTv) +
          (size_t)row * ors + oo + col0 + ci * 4) = make_float4(v[0], v[1], v[2], v[3]);
    }
  }
}

// ---------------------------------------------------------------------------
__global__ __launch_bounds__(256) void k_build_efm(
    const float* __restrict__ edge_feats, const float* __restrict__ mm_inv,
    const int* __restrict__ snd, float* __restrict__ efm)
{
  const int t = blockIdx.x * 256 + threadIdx.x;
  const int e = t >> 2, q = t & 3;
  float4 val;
  if (q < 2) {
    val = reinterpret_cast<const float4*>(edge_feats)[e * 2 + q];
  } else {
    const int s = snd[e];
    val = reinterpret_cast<const float4*>(mm_inv)[s * 2 + (q - 2)];
  }
  reinterpret_cast<float4*>(efm)[e * 4 + q] = val;
}

// ---------------------------------------------------------------------------
// CSR build
// ---------------------------------------------------------------------------
__global__ __launch_bounds__(256) void k_count(const int* __restrict__ rcv, int* __restrict__ counts) {
  const int e = blockIdx.x * 256 + threadIdx.x;
  atomicAdd(&counts[rcv[e]], 1);
}

__global__ __launch_bounds__(1024) void k_scan(const int* __restrict__ counts,
                                               int* __restrict__ offs, int* __restrict__ cursor) {
  __shared__ int part[1024];
  const int tid = threadIdx.x;
  int local[8];
  int s = 0;
  #pragma unroll
  for (int j = 0; j < 8; ++j) { local[j] = s; s += counts[tid * 8 + j]; }
  part[tid] = s;
  __syncthreads();
  for (int off = 1; off < 1024; off <<= 1) {
    int v = 0;
    if (tid >= off) v = part[tid - off];
    __syncthreads();
    part[tid] += v;
    __syncthreads();
  }
  const int base = part[tid] - s;
  #pragma unroll
  for (int j = 0; j < 8; ++j) {
    const int o = base + local[j];
    offs[tid * 8 + j] = o;
    cursor[tid * 8 + j] = o;
  }
  if (tid == 1023) offs[NN] = part[1023];
}

__global__ __launch_bounds__(256) void k_fill(const int* __restrict__ rcv,
                                              int* __restrict__ cursor, int* __restrict__ perm) {
  const int e = blockIdx.x * 256 + threadIdx.x;
  const int pos = atomicAdd(&cursor[rcv[e]], 1);
  perm[pos] = e;
}

// ---------------------------------------------------------------------------
// Gather: one wave per node, lane = channel u. Software-pipelined edge loop.
// ---------------------------------------------------------------------------
__global__ __launch_bounds__(256) void k_gather(
    const int* __restrict__ snd_idx,
    const float* __restrict__ edge_attrs,
    const float* __restrict__ edge_feats,
    const float* __restrict__ mm_attrs,
    const float* __restrict__ dens_w,
    const float* __restrict__ s_buf,
    const float* __restrict__ v_buf,
    const __hip_bfloat16* __restrict__ tp,
    const __hip_bfloat16* __restrict__ wmb,
    const int* __restrict__ offs,
    const int* __restrict__ perm,
    float* __restrict__ ms,
    float* __restrict__ mv,
    float* __restrict__ dens)
{
  const int n = (blockIdx.x * 256 + threadIdx.x) >> 6;
  const int lane = threadIdx.x & 63;
  if (n >= NN) return;
  float dw[8];
  #pragma unroll
  for (int r = 0; r < 8; ++r) dw[r] = dens_w[r];
  float acc_s[5] = {0.f, 0.f, 0.f, 0.f, 0.f};
  float acc_v[8][3] = {};
  float dacc = 0.f;
  const int start = offs[n], end = offs[n + 1];

  int e_nx = 0, s_nx = 0;
  if (start < end) { e_nx = perm[start]; s_nx = snd_idx[e_nx]; }
  for (int idx = start; idx < end; ++idx) {
    const int e = e_nx, s = s_nx;
    if (idx + 1 < end) { e_nx = perm[idx + 1]; s_nx = snd_idx[e_nx]; }

    const float4 ya = *reinterpret_cast<const float4*>(&edge_attrs[e * 4]);
    const float4 mm = *reinterpret_cast<const float4*>(&mm_attrs[s * 4]);
    const float4 ef0 = *reinterpret_cast<const float4*>(&edge_feats[e * 8]);
    const float4 ef1 = *reinterpret_cast<const float4*>(&edge_feats[e * 8 + 4]);
    const float y0 = ya.x, y1x = ya.y, y1y = ya.z, y1z = ya.w;
    const float m0 = mm.x, m1x = mm.y, m1y = mm.z, m1z = mm.w;
    float q = ef0.x * dw[0] + ef0.y * dw[1] + ef0.z * dw[2] + ef0.w * dw[3]
            + ef1.x * dw[4] + ef1.y * dw[5] + ef1.z * dw[6] + ef1.w * dw[7];
    q *= 0.35355339059f;
    dacc += tanhf(q * q);
    const float xs  = s_buf[s * 64 + lane];
    const float xvx = v_buf[(s * 3 + 0) * 64 + lane];
    const float xvy = v_buf[(s * 3 + 1) * 64 + lane];
    const float xvz = v_buf[(s * 3 + 2) * 64 + lane];
    float tpv[5];
    #pragma unroll
    for (int j = 0; j < 5; ++j) tpv[j] = __bfloat162float(tp[(size_t)e * 320 + j * 64 + lane]);
    float wv[13];
    #pragma unroll
    for (int p = 0; p < 13; ++p) wv[p] = __bfloat162float(wmb[(size_t)e * 832 + p * 64 + lane]);

    const float ms0  = tpv[0] * xs * y0;
    const float mv0x = tpv[1] * xs * y1x, mv0y = tpv[1] * xs * y1y, mv0z = tpv[1] * xs * y1z;
    const float mv1x = tpv[2] * xvx * y0, mv1y = tpv[2] * xvy * y0, mv1z = tpv[2] * xvz * y0;
    const float ms1  = tpv[3] * (xvx * y1x + xvy * y1y + xvz * y1z) * 0.57735026919f;
    const float crx = xvy * y1z - xvz * y1y;
    const float cry = xvz * y1x - xvx * y1z;
    const float crz = xvx * y1y - xvy * y1x;
    const float mv2x = tpv[4] * crx * 0.70710678119f;
    const float mv2y = tpv[4] * cry * 0.70710678119f;
    const float mv2z = tpv[4] * crz * 0.70710678119f;

    acc_s[0]    += wv[0] * ms0 * m0;
    acc_v[0][0] += wv[1] * ms0 * m1x; acc_v[0][1] += wv[1] * ms0 * m1y; acc_v[0][2] += wv[1] * ms0 * m1z;
    acc_s[1]    += wv[2] * ms1 * m0;
    acc_v[1][0] += wv[3] * ms1 * m1x; acc_v[1][1] += wv[3] * ms1 * m1y; acc_v[1][2] += wv[3] * ms1 * m1z;

#define VV_BLOCK(vx, vy, vz, pw, vslotA, sslot, vslotB)                                   \
    acc_v[vslotA][0] += wv[pw] * (vx) * m0;                                               \
    acc_v[vslotA][1] += wv[pw] * (vy) * m0;                                               \
    acc_v[vslotA][2] += wv[pw] * (vz) * m0;                                               \
    acc_s[sslot] += wv[pw + 1] * ((vx) * m1x + (vy) * m1y + (vz) * m1z) * 0.57735026919f; \
    {                                                                                     \
      const float ccx = (vy) * m1z - (vz) * m1y;                                          \
      const float ccy = (vz) * m1x - (vx) * m1z;                                          \
      const float ccz = (vx) * m1y - (vy) * m1x;                                          \
      acc_v[vslotB][0] += wv[pw + 2] * ccx * 0.70710678119f;                              \
      acc_v[vslotB][1] += wv[pw + 2] * ccy * 0.70710678119f;                              \
      acc_v[vslotB][2] += wv[pw + 2] * ccz * 0.70710678119f;                              \
    }

    VV_BLOCK(mv0x, mv0y, mv0z, 4, 2, 2, 3)
    VV_BLOCK(mv1x, mv1y, mv1z, 7, 4, 3, 5)
    VV_BLOCK(mv2x, mv2y, mv2z, 10, 6, 4, 7)
#undef VV_BLOCK
  }
  #pragma unroll
  for (int j = 0; j < 5; ++j) ms[(size_t)n * 320 + j * 64 + lane] = acc_s[j];
  #pragma unroll
  for (int p = 0; p < 8; ++p)
    #pragma unroll
    for (int i = 0; i < 3; ++i)
      mv[((size_t)n * 3 + i) * 512 + p * 64 + lane] = acc_v[p][i];
  if (lane == 0) dens[n] = dacc;
}

// ---------------------------------------------------------------------------
// Skip contraction -> final output (N, 64, 4)
// ---------------------------------------------------------------------------
__global__ __launch_bounds__(256) void k_skip(
    const float* __restrict__ ms2, const float* __restrict__ mv2,
    const float* __restrict__ na,
    const float* __restrict__ Ss, const float* __restrict__ Sv,
    float* __restrict__ out)
{
  const int wave = (blockIdx.x * 256 + threadIdx.x) >> 6;
  const int lane = threadIdx.x & 63;
  const int nb = wave * 4;
  float nav[4][10];
  #pragma unroll
  for (int t = 0; t < 4; ++t)
    #pragma unroll
    for (int v = 0; v < 10; ++v) nav[t][v] = na[(nb + t) * 10 + v];
  float os[4] = {0.f, 0.f, 0.f, 0.f};
  float ov[4][3] = {};
  for (int u = 0; u < 64; ++u) {
    float ssr[10], svr[10];
    #pragma unroll
    for (int v = 0; v < 10; ++v) ssr[v] = Ss[(u * 10 + v) * 64 + lane];
    #pragma unroll
    for (int v = 0; v < 10; ++v) svr[v] = Sv[(u * 10 + v) * 64 + lane];
    #pragma unroll
    for (int t = 0; t < 4; ++t) {
      float bs = 0.f, bv = 0.f;
      #pragma unroll
      for (int v = 0; v < 10; ++v) { bs += nav[t][v] * ssr[v]; bv += nav[t][v] * svr[v]; }
      os[t] += ms2[(nb + t) * 64 + u] * bs;
      #pragma unroll
      for (int i = 0; i < 3; ++i) ov[t][i] += mv2[((nb + t) * 3 + i) * 64 + u] * bv;
    }
  }
  const float inv_fan = 0.03952847075f;
  #pragma unroll
  for (int t = 0; t < 4; ++t) {
    const int n = nb + t;
    const size_t base = ((size_t)(n * 64 + lane)) * 4;
    out[base + 0] = os[t] * inv_fan;
    out[base + 1] = ov[t][0] * inv_fan;
    out[base + 2] = ov[t][1] * inv_fan;
    out[base + 3] = ov[t][2] * inv_fan;
  }
}

// ---------------------------------------------------------------------------
extern "C" void kernel_launch(void* const* d_in, const int* in_sizes, int n_in,
                              void* d_out, int out_size, void* d_ws, size_t ws_size,
                              hipStream_t stream)
{
  const float* node_attrs = (const float*)d_in[0];
  const float* node_feats = (const float*)d_in[1];
  const float* edge_attrs = (const float*)d_in[2];
  const float* edge_feats = (const float*)d_in[3];
  const int*   edge_index = (const int*)d_in[4];
  const float* mm_inv     = (const float*)d_in[5];
  const float* mm_attrs   = (const float*)d_in[6];
  const float* W_up_s     = (const float*)d_in[7];
  const float* W_up_v     = (const float*)d_in[8];
  const float* w0         = (const float*)d_in[9];
  const float* w1         = (const float*)d_in[10];
  const float* w2         = (const float*)d_in[11];
  const float* w3         = (const float*)d_in[12];
  const float* mag_w      = (const float*)d_in[13];
  const float* dens_w     = (const float*)d_in[14];
  const float* lin_s      = (const float*)d_in[15];
  const float* lin_v      = (const float*)d_in[16];
  const float* skip_s     = (const float*)d_in[17];
  const float* skip_v     = (const float*)d_in[18];
  float* out = (float*)d_out;

  char* wp = (char*)d_ws;
  auto alloc = [&](size_t b) { char* p = wp; wp += (b + 255) & ~(size_t)255; return p; };
  float* s_buf  = (float*)alloc((size_t)NN * 64 * 4);
  float* v_buf  = (float*)alloc((size_t)NN * 192 * 4);
  float* efm    = (float*)alloc((size_t)EE * 16 * 4);
  float* h_a    = (float*)alloc((size_t)EE * 64 * 4);
  float* h_b    = (float*)alloc((size_t)EE * 64 * 4);
  u16*   tp     = (u16*)alloc((size_t)EE * 320 * 2);
  u16*   wmb    = (u16*)alloc((size_t)EE * 832 * 2);
  float* ms     = (float*)alloc((size_t)NN * 320 * 4);
  float* mv     = (float*)alloc((size_t)NN * 1536 * 4);
  float* ms2    = (float*)alloc((size_t)NN * 64 * 4);
  float* mv2    = (float*)alloc((size_t)NN * 192 * 4);
  float* dens   = (float*)alloc((size_t)NN * 4);
  int*   counts = (int*)alloc((size_t)NN * 4);
  int*   offs   = (int*)alloc((size_t)(NN + 1) * 4);
  int*   cursor = (int*)alloc((size_t)NN * 4);
  int*   perm   = (int*)alloc((size_t)EE * 4);

  const int* snd = edge_index;
  const int* rcv = edge_index + EE;

  hipMemsetAsync(counts, 0, (size_t)NN * 4, stream);
  k_build_efm<<<EE * 4 / 256, 256, 0, stream>>>(edge_feats, mm_inv, snd, efm);
  k_count<<<EE / 256, 256, 0, stream>>>(rcv, counts);
  k_scan<<<1, 1024, 0, stream>>>(counts, offs, cursor);
  k_fill<<<EE / 256, 256, 0, stream>>>(rcv, cursor, perm);

  // node up-projections (fp32 path)
  k_gemm<32, false, false><<<dim3(NN / 32, 1, 1), 256, 0, stream>>>(
      node_feats, 256, 1, 0, 0, W_up_s, 64, 64, 0.125f, s_buf, 64, 0, nullptr);
  k_gemm<32, false, false><<<dim3(NN / 32, 1, 3), 256, 0, stream>>>(
      node_feats, 256, 3, 64, 1, W_up_v, 64, 64, 0.125f, v_buf, 192, 64, nullptr);

  // edge radial MLP + mag weights: MFMA with 3-term bf16 split (fp32-equiv)
  k_mgemm<true,  false><<<dim3(EE / 128, 1),  256, 0, stream>>>(efm, 16, w0, 16, 64,  0.25f,  h_a, 64,  nullptr);
  k_mgemm<true,  false><<<dim3(EE / 128, 1),  256, 0, stream>>>(h_a, 64, w1, 64, 64,  0.125f, h_b, 64,  nullptr);
  k_mgemm<true,  false><<<dim3(EE / 128, 1),  256, 0, stream>>>(h_b, 64, w2, 64, 64,  0.125f, h_a, 64,  nullptr);
  k_mgemm<false, true ><<<dim3(EE / 128, 5),  256, 0, stream>>>(h_a, 64, w3, 64, 320, 0.125f, tp,  320, nullptr);
  k_mgemm<false, true ><<<dim3(EE / 128, 13), 256, 0, stream>>>(efm, 16, mag_w, 16, 832, 0.25f, wmb, 832, nullptr);

  // per-node gather + tensor product + segment sum (no atomics)
  k_gather<<<NN / 4, 256, 0, stream>>>(snd, edge_attrs, edge_feats, mm_attrs, dens_w,
                                       s_buf, v_buf,
                                       (const __hip_bfloat16*)tp, (const __hip_bfloat16*)wmb,
                                       offs, perm, ms, mv, dens);

  // node linears (fp32 path) with density division fused
  k_gemm<32, false, false><<<dim3(NN / 32, 1, 1), 256, 0, stream>>>(
      ms, 320, 1, 0, 0, lin_s, 320, 64, 0.05590169944f, ms2, 64, 0, dens);
  k_gemm<32, false, false><<<dim3(NN / 32, 1, 3), 256, 0, stream>>>(
      mv, 1536, 1, 0, 512, lin_v, 512, 64, 0.04419417382f, mv2, 192, 64, dens);

  // skip contraction -> final output (N, 64, 4)
  k_skip<<<NN / 16, 256, 0, stream>>>(ms2, mv2, node_attrs, skip_s, skip_v, out);
}

// Round 4
// 436.511 us; speedup vs baseline: 1.7506x; 1.0320x over previous
//
#include <hip/hip_runtime.h>
#include <hip/hip_bf16.h>

#define NN 8192
#define EE 65536

typedef unsigned short u16;
typedef __attribute__((ext_vector_type(8))) short bf16x8;   // 8 bf16 = 4 VGPRs
typedef __attribute__((ext_vector_type(4))) float f32x4;

__device__ __forceinline__ u16 f2bf(float f) {
  __hip_bfloat16 h = __float2bfloat16(f);
  return *reinterpret_cast<u16*>(&h);
}
__device__ __forceinline__ float bf2f(u16 v) {
  union { unsigned int u; float f; } x; x.u = ((unsigned int)v) << 16; return x.f;
}
__device__ __forceinline__ void split2(float x, u16& h, u16& l) {
  __hip_bfloat16 bh = __float2bfloat16(x);
  h = *reinterpret_cast<u16*>(&bh);
  float r = x - __bfloat162float(bh);
  __hip_bfloat16 bl = __float2bfloat16(r);
  l = *reinterpret_cast<u16*>(&bl);
}

// ---------------------------------------------------------------------------
// MFMA GEMM, fp32-equivalent via 3-term bf16 split (Ah*Bh + Ah*Bl + Al*Bh).
// A arrives PRE-SPLIT as bf16 hi/lo pair (no split math in staging — pure
// 16B copies). B (small weights) split in-kernel. Tile 128x64, 4 waves.
// OUT: 1 = split bf16 pair (hi+lo ~ fp32), 2 = single bf16.
// ---------------------------------------------------------------------------
template<int OUT, bool SILU>
__global__ __launch_bounds__(256) void k_mgemm(
    const u16* __restrict__ Xh, const u16* __restrict__ Xl, int xrs,
    const float* __restrict__ W, int K, int NOUT, float scale,
    u16* __restrict__ Oh, u16* __restrict__ Ol, int ors)
{
  __shared__ u16 Ah[128 * 40];   // rows padded 32->40 elems (80 B = 5x16 B)
  __shared__ u16 Al[128 * 40];
  __shared__ u16 Bh[64 * 40];    // stored transposed: Bt[n][k]
  __shared__ u16 Bl[64 * 40];
  const int tid  = threadIdx.x;
  const int row0 = blockIdx.x * 128;
  const int col0 = blockIdx.y * 64;
  const int wave = tid >> 6, lane = tid & 63;
  const int quad = lane >> 4, lrow = lane & 15;
  const int kbase = quad * 8;

  f32x4 acc[2][4] = {};

  for (int k0 = 0; k0 < K; k0 += 32) {
    // ---- stage A: copy pre-split bf16, 16B chunks, zero-pad past K ----
    // 128 rows x 4 chunks(8 u16) x 2 buffers = 1024 chunk-writes / 256 thr
    #pragma unroll
    for (int i = 0; i < 4; ++i) {
      const int idx = tid + i * 256;
      const int b = idx >> 9, rc = idx & 511;
      const int r = rc >> 2, c = rc & 3;
      const u16* src = b ? Xl : Xh;
      uint4 v = make_uint4(0u, 0u, 0u, 0u);
      if (k0 + c * 8 < K)
        v = *reinterpret_cast<const uint4*>(&src[(size_t)(row0 + r) * xrs + k0 + c * 8]);
      *reinterpret_cast<uint4*>(&(b ? Al : Ah)[r * 40 + c * 8]) = v;
    }
    // ---- stage B (32 x 64 fp32 -> split bf16, transposed) ----
    #pragma unroll
    for (int i = 0; i < 8; ++i) {
      const int idx = tid + i * 256;          // 2048 elems
      const int k = idx >> 6, n = idx & 63;
      float v = 0.f;
      if (k0 + k < K) v = W[(size_t)(k0 + k) * NOUT + col0 + n];
      u16 hh, ll;
      split2(v, hh, ll);
      Bh[n * 40 + k] = hh;
      Bl[n * 40 + k] = ll;
    }
    __syncthreads();

    bf16x8 fah[2], fal[2], fbh[4], fbl[4];
    #pragma unroll
    for (int mt = 0; mt < 2; ++mt) {
      const int ro = (wave * 32 + mt * 16 + lrow) * 40 + kbase;
      fah[mt] = *reinterpret_cast<const bf16x8*>(&Ah[ro]);
      fal[mt] = *reinterpret_cast<const bf16x8*>(&Al[ro]);
    }
    #pragma unroll
    for (int nt = 0; nt < 4; ++nt) {
      const int ro = (nt * 16 + lrow) * 40 + kbase;
      fbh[nt] = *reinterpret_cast<const bf16x8*>(&Bh[ro]);
      fbl[nt] = *reinterpret_cast<const bf16x8*>(&Bl[ro]);
    }
    #pragma unroll
    for (int mt = 0; mt < 2; ++mt)
      #pragma unroll
      for (int nt = 0; nt < 4; ++nt) {
        acc[mt][nt] = __builtin_amdgcn_mfma_f32_16x16x32_bf16(fah[mt], fbh[nt], acc[mt][nt], 0, 0, 0);
        acc[mt][nt] = __builtin_amdgcn_mfma_f32_16x16x32_bf16(fah[mt], fbl[nt], acc[mt][nt], 0, 0, 0);
        acc[mt][nt] = __builtin_amdgcn_mfma_f32_16x16x32_bf16(fal[mt], fbh[nt], acc[mt][nt], 0, 0, 0);
      }
    __syncthreads();
  }

  // ---- epilogue: C/D layout col=lane&15, row=quad*4+reg ----
  #pragma unroll
  for (int mt = 0; mt < 2; ++mt)
    #pragma unroll
    for (int nt = 0; nt < 4; ++nt)
      #pragma unroll
      for (int r = 0; r < 4; ++r) {
        const int grow = row0 + wave * 32 + mt * 16 + quad * 4 + r;
        const int gcol = col0 + nt * 16 + lrow;
        float t = acc[mt][nt][r] * scale;
        if (SILU) t = t / (1.0f + __expf(-t));
        const size_t oi = (size_t)grow * ors + gcol;
        if (OUT == 1) {
          u16 hh, ll;
          split2(t, hh, ll);
          Oh[oi] = hh; Ol[oi] = ll;
        } else {
          Oh[oi] = f2bf(t);
        }
      }
}

// ---------------------------------------------------------------------------
// fp32 tiled GEMM (node-side GEMMs): OUT = post(scale * X@W)
// ---------------------------------------------------------------------------
template<int RT, bool SILU, bool OUT_BF16>
__global__ __launch_bounds__(256) void k_gemm(
    const float* __restrict__ X, int xrs, int xes, int xco, int xcob,
    const float* __restrict__ W, int K, int NOUT,
    float scale, void* __restrict__ OUTv, int ors, int oob,
    const float* __restrict__ dens)
{
  constexpr int RPT = RT / 16;
  __shared__ float Xs[RT * 65];
  __shared__ float Ws[64 * 64];
  const int tid  = threadIdx.x;
  const int row0 = blockIdx.x * RT;
  const int col0 = blockIdx.y * 64;
  const int z    = blockIdx.z;
  const int xc   = xco + z * xcob;
  const int oo   = z * oob;
  const int ci = tid & 15;
  const int ri = tid >> 4;
  float acc[RPT][4] = {};

  for (int k0 = 0; k0 < K; k0 += 64) {
    const int kc  = (K - k0 >= 64) ? 64 : (K - k0);
    const int ksh = (kc == 64) ? 6 : 4;
    for (int idx = tid; idx < kc * RT; idx += 256) {
      const int r = idx >> ksh, kk = idx & (kc - 1);
      Xs[r * 65 + kk] = X[(size_t)(row0 + r) * xrs + xc + (size_t)(k0 + kk) * xes];
    }
    for (int idx = tid; idx < (kc << 6); idx += 256) {
      const int kk = idx >> 6, c = idx & 63;
      Ws[kk * 64 + c] = W[(size_t)(k0 + kk) * NOUT + col0 + c];
    }
    __syncthreads();
    for (int kk = 0; kk < kc; ++kk) {
      const float4 wv = *reinterpret_cast<const float4*>(&Ws[kk * 64 + ci * 4]);
      #pragma unroll
      for (int j = 0; j < RPT; ++j) {
        const float x = Xs[(ri * RPT + j) * 65 + kk];
        acc[j][0] += x * wv.x; acc[j][1] += x * wv.y;
        acc[j][2] += x * wv.z; acc[j][3] += x * wv.w;
      }
    }
    __syncthreads();
  }

  #pragma unroll
  for (int j = 0; j < RPT; ++j) {
    const int row = row0 + ri * RPT + j;
    float post = 1.0f;
    if (dens) post = 1.0f / (dens[row] + 1.0f);
    float v[4];
    #pragma unroll
    for (int q = 0; q < 4; ++q) {
      float t = acc[j][q] * scale;
      if (SILU) t = t / (1.0f + __expf(-t));
      v[q] = t * post;
    }
    if (OUT_BF16) {
      ushort4 pk;
      pk.x = f2bf(v[0]); pk.y = f2bf(v[1]); pk.z = f2bf(v[2]); pk.w = f2bf(v[3]);
      *reinterpret_cast<ushort4*>(reinterpret_cast<u16*>(OUTv) +
          (size_t)row * ors + oo + col0 + ci * 4) = pk;
    } else {
      *reinterpret_cast<float4*>(reinterpret_cast<float*>(OUTv) +
          (size_t)row * ors + oo + col0 + ci * 4) = make_float4(v[0], v[1], v[2], v[3]);
    }
  }
}

// ---------------------------------------------------------------------------
// CSR build
// ---------------------------------------------------------------------------
__global__ __launch_bounds__(256) void k_count(const int* __restrict__ rcv, int* __restrict__ counts) {
  const int e = blockIdx.x * 256 + threadIdx.x;
  atomicAdd(&counts[rcv[e]], 1);
}

__global__ __launch_bounds__(1024) void k_scan(const int* __restrict__ counts,
                                               int* __restrict__ offs, int* __restrict__ cursor) {
  __shared__ int part[1024];
  const int tid = threadIdx.x;
  int local[8];
  int s = 0;
  #pragma unroll
  for (int j = 0; j < 8; ++j) { local[j] = s; s += counts[tid * 8 + j]; }
  part[tid] = s;
  __syncthreads();
  for (int off = 1; off < 1024; off <<= 1) {
    int v = 0;
    if (tid >= off) v = part[tid - off];
    __syncthreads();
    part[tid] += v;
    __syncthreads();
  }
  const int base = part[tid] - s;
  #pragma unroll
  for (int j = 0; j < 8; ++j) {
    const int o = base + local[j];
    offs[tid * 8 + j] = o;
    cursor[tid * 8 + j] = o;
  }
  if (tid == 1023) offs[NN] = part[1023];
}

__global__ __launch_bounds__(256) void k_fill(const int* __restrict__ rcv,
                                              int* __restrict__ cursor, int* __restrict__ perm) {
  const int e = blockIdx.x * 256 + threadIdx.x;
  const int pos = atomicAdd(&cursor[rcv[e]], 1);
  perm[pos] = e;
}

// ---------------------------------------------------------------------------
// Permute edge data into receiver-grouped (perm) order + precompute:
//   snd_perm, ya_perm (edge_attrs), dq_perm (tanh(q^2)), efm split pair.
// After this, the whole edge pipeline is sequential in pos.
// ---------------------------------------------------------------------------
__global__ __launch_bounds__(256) void k_build(
    const int* __restrict__ perm, const int* __restrict__ snd,
    const float* __restrict__ edge_attrs, const float* __restrict__ edge_feats,
    const float* __restrict__ mm_inv, const float* __restrict__ dens_w,
    int* __restrict__ snd_perm, float* __restrict__ ya_perm,
    float* __restrict__ dq_perm, u16* __restrict__ efm_h, u16* __restrict__ efm_l)
{
  const int pos = blockIdx.x * 256 + threadIdx.x;
  const int e = perm[pos];
  const int s = snd[e];
  snd_perm[pos] = s;
  reinterpret_cast<float4*>(ya_perm)[pos] = reinterpret_cast<const float4*>(edge_attrs)[e];
  const float4 ef0 = reinterpret_cast<const float4*>(edge_feats)[e * 2];
  const float4 ef1 = reinterpret_cast<const float4*>(edge_feats)[e * 2 + 1];
  const float4 mi0 = reinterpret_cast<const float4*>(mm_inv)[s * 2];
  const float4 mi1 = reinterpret_cast<const float4*>(mm_inv)[s * 2 + 1];
  float q = ef0.x * dens_w[0] + ef0.y * dens_w[1] + ef0.z * dens_w[2] + ef0.w * dens_w[3]
          + ef1.x * dens_w[4] + ef1.y * dens_w[5] + ef1.z * dens_w[6] + ef1.w * dens_w[7];
  q *= 0.35355339059f;   // 1/sqrt(8)
  dq_perm[pos] = tanhf(q * q);
  float vals[16] = { ef0.x, ef0.y, ef0.z, ef0.w, ef1.x, ef1.y, ef1.z, ef1.w,
                     mi0.x, mi0.y, mi0.z, mi0.w, mi1.x, mi1.y, mi1.z, mi1.w };
  u16 hh[16], ll[16];
  #pragma unroll
  for (int i = 0; i < 16; ++i) split2(vals[i], hh[i], ll[i]);
  reinterpret_cast<uint4*>(&efm_h[(size_t)pos * 16])[0] = reinterpret_cast<uint4*>(hh)[0];
  reinterpret_cast<uint4*>(&efm_h[(size_t)pos * 16])[1] = reinterpret_cast<uint4*>(hh)[1];
  reinterpret_cast<uint4*>(&efm_l[(size_t)pos * 16])[0] = reinterpret_cast<uint4*>(ll)[0];
  reinterpret_cast<uint4*>(&efm_l[(size_t)pos * 16])[1] = reinterpret_cast<uint4*>(ll)[1];
}

// ---------------------------------------------------------------------------
// Gather: one wave per node, lane = channel u. All per-edge streams (ya, dq,
// snd, tp, wm) are sequential in pos; only mm_attrs/s_buf/v_buf are random
// (small, L2/L3-resident).
// ---------------------------------------------------------------------------
__global__ __launch_bounds__(256) void k_gather(
    const int* __restrict__ snd_perm,
    const float* __restrict__ ya_perm,
    const float* __restrict__ dq_perm,
    const float* __restrict__ mm_attrs,
    const float* __restrict__ s_buf,
    const float* __restrict__ v_buf,
    const u16* __restrict__ tp,
    const u16* __restrict__ wmb,
    const int* __restrict__ offs,
    float* __restrict__ ms,
    float* __restrict__ mv,
    float* __restrict__ dens)
{
  const int n = (blockIdx.x * 256 + threadIdx.x) >> 6;
  const int lane = threadIdx.x & 63;
  if (n >= NN) return;
  float acc_s[5] = {0.f, 0.f, 0.f, 0.f, 0.f};
  float acc_v[8][3] = {};
  float dacc = 0.f;
  const int start = offs[n], end = offs[n + 1];

  int s_nx = 0;
  if (start < end) s_nx = snd_perm[start];
  for (int pos = start; pos < end; ++pos) {
    const int s = s_nx;
    if (pos + 1 < end) s_nx = snd_perm[pos + 1];

    const float4 ya = reinterpret_cast<const float4*>(ya_perm)[pos];
    const float4 mm = reinterpret_cast<const float4*>(mm_attrs)[s];
    dacc += dq_perm[pos];
    const float y0 = ya.x, y1x = ya.y, y1y = ya.z, y1z = ya.w;
    const float m0 = mm.x, m1x = mm.y, m1y = mm.z, m1z = mm.w;
    const float xs  = s_buf[s * 64 + lane];
    const float xvx = v_buf[(s * 3 + 0) * 64 + lane];
    const float xvy = v_buf[(s * 3 + 1) * 64 + lane];
    const float xvz = v_buf[(s * 3 + 2) * 64 + lane];
    float tpv[5];
    #pragma unroll
    for (int j = 0; j < 5; ++j) tpv[j] = bf2f(tp[(size_t)pos * 320 + j * 64 + lane]);
    float wv[13];
    #pragma unroll
    for (int p = 0; p < 13; ++p) wv[p] = bf2f(wmb[(size_t)pos * 832 + p * 64 + lane]);

    const float ms0  = tpv[0] * xs * y0;
    const float mv0x = tpv[1] * xs * y1x, mv0y = tpv[1] * xs * y1y, mv0z = tpv[1] * xs * y1z;
    const float mv1x = tpv[2] * xvx * y0, mv1y = tpv[2] * xvy * y0, mv1z = tpv[2] * xvz * y0;
    const float ms1  = tpv[3] * (xvx * y1x + xvy * y1y + xvz * y1z) * 0.57735026919f;
    const float crx = xvy * y1z - xvz * y1y;
    const float cry = xvz * y1x - xvx * y1z;
    const float crz = xvx * y1y - xvy * y1x;
    const float mv2x = tpv[4] * crx * 0.70710678119f;
    const float mv2y = tpv[4] * cry * 0.70710678119f;
    const float mv2z = tpv[4] * crz * 0.70710678119f;

    acc_s[0]    += wv[0] * ms0 * m0;
    acc_v[0][0] += wv[1] * ms0 * m1x; acc_v[0][1] += wv[1] * ms0 * m1y; acc_v[0][2] += wv[1] * ms0 * m1z;
    acc_s[1]    += wv[2] * ms1 * m0;
    acc_v[1][0] += wv[3] * ms1 * m1x; acc_v[1][1] += wv[3] * ms1 * m1y; acc_v[1][2] += wv[3] * ms1 * m1z;

#define VV_BLOCK(vx, vy, vz, pw, vslotA, sslot, vslotB)                                   \
    acc_v[vslotA][0] += wv[pw] * (vx) * m0;                                               \
    acc_v[vslotA][1] += wv[pw] * (vy) * m0;                                               \
    acc_v[vslotA][2] += wv[pw] * (vz) * m0;                                               \
    acc_s[sslot] += wv[pw + 1] * ((vx) * m1x + (vy) * m1y + (vz) * m1z) * 0.57735026919f; \
    {                                                                                     \
      const float ccx = (vy) * m1z - (vz) * m1y;                                          \
      const float ccy = (vz) * m1x - (vx) * m1z;                                          \
      const float ccz = (vx) * m1y - (vy) * m1x;                                          \
      acc_v[vslotB][0] += wv[pw + 2] * ccx * 0.70710678119f;                              \
      acc_v[vslotB][1] += wv[pw + 2] * ccy * 0.70710678119f;                              \
      acc_v[vslotB][2] += wv[pw + 2] * ccz * 0.70710678119f;                              \
    }

    VV_BLOCK(mv0x, mv0y, mv0z, 4, 2, 2, 3)
    VV_BLOCK(mv1x, mv1y, mv1z, 7, 4, 3, 5)
    VV_BLOCK(mv2x, mv2y, mv2z, 10, 6, 4, 7)
#undef VV_BLOCK
  }
  #pragma unroll
  for (int j = 0; j < 5; ++j) ms[(size_t)n * 320 + j * 64 + lane] = acc_s[j];
  #pragma unroll
  for (int p = 0; p < 8; ++p)
    #pragma unroll
    for (int i = 0; i < 3; ++i)
      mv[((size_t)n * 3 + i) * 512 + p * 64 + lane] = acc_v[p][i];
  if (lane == 0) dens[n] = dacc;
}

// ---------------------------------------------------------------------------
// Skip contraction -> final output (N, 64, 4)
// ---------------------------------------------------------------------------
__global__ __launch_bounds__(256) void k_skip(
    const float* __restrict__ ms2, const float* __restrict__ mv2,
    const float* __restrict__ na,
    const float* __restrict__ Ss, const float* __restrict__ Sv,
    float* __restrict__ out)
{
  const int wave = (blockIdx.x * 256 + threadIdx.x) >> 6;
  const int lane = threadIdx.x & 63;
  const int nb = wave * 4;
  float nav[4][10];
  #pragma unroll
  for (int t = 0; t < 4; ++t)
    #pragma unroll
    for (int v = 0; v < 10; ++v) nav[t][v] = na[(nb + t) * 10 + v];
  float os[4] = {0.f, 0.f, 0.f, 0.f};
  float ov[4][3] = {};
  for (int u = 0; u < 64; ++u) {
    float ssr[10], svr[10];
    #pragma unroll
    for (int v = 0; v < 10; ++v) ssr[v] = Ss[(u * 10 + v) * 64 + lane];
    #pragma unroll
    for (int v = 0; v < 10; ++v) svr[v] = Sv[(u * 10 + v) * 64 + lane];
    #pragma unroll
    for (int t = 0; t < 4; ++t) {
      float bs = 0.f, bv = 0.f;
      #pragma unroll
      for (int v = 0; v < 10; ++v) { bs += nav[t][v] * ssr[v]; bv += nav[t][v] * svr[v]; }
      os[t] += ms2[(nb + t) * 64 + u] * bs;
      #pragma unroll
      for (int i = 0; i < 3; ++i) ov[t][i] += mv2[((nb + t) * 3 + i) * 64 + u] * bv;
    }
  }
  const float inv_fan = 0.03952847075f;
  #pragma unroll
  for (int t = 0; t < 4; ++t) {
    const int n = nb + t;
    const size_t base = ((size_t)(n * 64 + lane)) * 4;
    out[base + 0] = os[t] * inv_fan;
    out[base + 1] = ov[t][0] * inv_fan;
    out[base + 2] = ov[t][1] * inv_fan;
    out[base + 3] = ov[t][2] * inv_fan;
  }
}

// ---------------------------------------------------------------------------
extern "C" void kernel_launch(void* const* d_in, const int* in_sizes, int n_in,
                              void* d_out, int out_size, void* d_ws, size_t ws_size,
                              hipStream_t stream)
{
  const float* node_attrs = (const float*)d_in[0];
  const float* node_feats = (const float*)d_in[1];
  const float* edge_attrs = (const float*)d_in[2];
  const float* edge_feats = (const float*)d_in[3];
  const int*   edge_index = (const int*)d_in[4];
  const float* mm_inv     = (const float*)d_in[5];
  const float* mm_attrs   = (const float*)d_in[6];
  const float* W_up_s     = (const float*)d_in[7];
  const float* W_up_v     = (const float*)d_in[8];
  const float* w0         = (const float*)d_in[9];
  const float* w1         = (const float*)d_in[10];
  const float* w2         = (const float*)d_in[11];
  const float* w3         = (const float*)d_in[12];
  const float* mag_w      = (const float*)d_in[13];
  const float* dens_w     = (const float*)d_in[14];
  const float* lin_s      = (const float*)d_in[15];
  const float* lin_v      = (const float*)d_in[16];
  const float* skip_s     = (const float*)d_in[17];
  const float* skip_v     = (const float*)d_in[18];
  float* out = (float*)d_out;

  char* wp = (char*)d_ws;
  auto alloc = [&](size_t b) { char* p = wp; wp += (b + 255) & ~(size_t)255; return p; };
  float* s_buf  = (float*)alloc((size_t)NN * 64 * 4);
  float* v_buf  = (float*)alloc((size_t)NN * 192 * 4);
  float* ya_p   = (float*)alloc((size_t)EE * 4 * 4);
  float* dq_p   = (float*)alloc((size_t)EE * 4);
  int*   snd_p  = (int*)alloc((size_t)EE * 4);
  u16*   efm_h  = (u16*)alloc((size_t)EE * 16 * 2);
  u16*   efm_l  = (u16*)alloc((size_t)EE * 16 * 2);
  u16*   hA_h   = (u16*)alloc((size_t)EE * 64 * 2);
  u16*   hA_l   = (u16*)alloc((size_t)EE * 64 * 2);
  u16*   hB_h   = (u16*)alloc((size_t)EE * 64 * 2);
  u16*   hB_l   = (u16*)alloc((size_t)EE * 64 * 2);
  u16*   tp     = (u16*)alloc((size_t)EE * 320 * 2);
  u16*   wmb    = (u16*)alloc((size_t)EE * 832 * 2);
  float* ms     = (float*)alloc((size_t)NN * 320 * 4);
  float* mv     = (float*)alloc((size_t)NN * 1536 * 4);
  float* ms2    = (float*)alloc((size_t)NN * 64 * 4);
  float* mv2    = (float*)alloc((size_t)NN * 192 * 4);
  float* dens   = (float*)alloc((size_t)NN * 4);
  int*   counts = (int*)alloc((size_t)NN * 4);
  int*   offs   = (int*)alloc((size_t)(NN + 1) * 4);
  int*   cursor = (int*)alloc((size_t)NN * 4);
  int*   perm   = (int*)alloc((size_t)EE * 4);

  const int* snd = edge_index;
  const int* rcv = edge_index + EE;

  // CSR + permuted edge data
  hipMemsetAsync(counts, 0, (size_t)NN * 4, stream);
  k_count<<<EE / 256, 256, 0, stream>>>(rcv, counts);
  k_scan<<<1, 1024, 0, stream>>>(counts, offs, cursor);
  k_fill<<<EE / 256, 256, 0, stream>>>(rcv, cursor, perm);
  k_build<<<EE / 256, 256, 0, stream>>>(perm, snd, edge_attrs, edge_feats, mm_inv, dens_w,
                                        snd_p, ya_p, dq_p, efm_h, efm_l);

  // node up-projections (fp32 path)
  k_gemm<32, false, false><<<dim3(NN / 32, 1, 1), 256, 0, stream>>>(
      node_feats, 256, 1, 0, 0, W_up_s, 64, 64, 0.125f, s_buf, 64, 0, nullptr);
  k_gemm<32, false, false><<<dim3(NN / 32, 1, 3), 256, 0, stream>>>(
      node_feats, 256, 3, 64, 1, W_up_v, 64, 64, 0.125f, v_buf, 192, 64, nullptr);

  // edge MLP chain on pre-split pairs (perm order)
  k_mgemm<1, true ><<<dim3(EE / 128, 1),  256, 0, stream>>>(efm_h, efm_l, 16, w0, 16, 64,  0.25f,  hA_h, hA_l, 64);
  k_mgemm<1, true ><<<dim3(EE / 128, 1),  256, 0, stream>>>(hA_h, hA_l, 64, w1, 64, 64,  0.125f, hB_h, hB_l, 64);
  k_mgemm<2, false><<<dim3(EE / 128, 13), 256, 0, stream>>>(efm_h, efm_l, 16, mag_w, 16, 832, 0.25f, wmb, nullptr, 832);
  k_mgemm<1, true ><<<dim3(EE / 128, 1),  256, 0, stream>>>(hB_h, hB_l, 64, w2, 64, 64,  0.125f, hA_h, hA_l, 64);
  k_mgemm<2, false><<<dim3(EE / 128, 5),  256, 0, stream>>>(hA_h, hA_l, 64, w3, 64, 320, 0.125f, tp, nullptr, 320);

  // per-node gather + tensor product + segment sum (sequential streams)
  k_gather<<<NN / 4, 256, 0, stream>>>(snd_p, ya_p, dq_p, mm_attrs,
                                       s_buf, v_buf, tp, wmb, offs, ms, mv, dens);

  // node linears (fp32 path) with density division fused
  k_gemm<32, false, false><<<dim3(NN / 32, 1, 1), 256, 0, stream>>>(
      ms, 320, 1, 0, 0, lin_s, 320, 64, 0.05590169944f, ms2, 64, 0, dens);
  k_gemm<32, false, false><<<dim3(NN / 32, 1, 3), 256, 0, stream>>>(
      mv, 1536, 1, 0, 512, lin_v, 512, 64, 0.04419417382f, mv2, 192, 64, dens);

  // skip contraction -> final output (N, 64, 4)
  k_skip<<<NN / 16, 256, 0, stream>>>(ms2, mv2, node_attrs, skip_s, skip_v, out);
}